// Round 9
// baseline (21289.061 us; speedup 1.0000x reference)
//
#include <hip/hip_runtime.h>

#define T_TOT 1024
#define BB 64
#define DD 128
#define HH 256
#define GG 1024
#define OO 64
#define LN_EPS 1e-3f

typedef unsigned int u32;
typedef _Float16 h2 __attribute__((ext_vector_type(2)));

__device__ __forceinline__ float fdot2(u32 a, u32 b, float c) {
  return __builtin_amdgcn_fdot2(__builtin_bit_cast(h2, a), __builtin_bit_cast(h2, b), c, false);
}
__device__ __forceinline__ u32 pkf16(float lo, float hi) {
  h2 v = { (_Float16)lo, (_Float16)hi };
  return __builtin_bit_cast(u32, v);
}
__device__ __forceinline__ float fast_sigmoid(float x) { return 1.0f / (1.0f + __expf(-x)); }
__device__ __forceinline__ float fast_tanh(float x) { return 2.0f / (1.0f + __expf(-2.0f * x)) - 1.0f; }

// ---------------- prep: pack Wh (4H x H) into f16 pairs, chunked by 8 along H ----
__global__ void prep_wh(const float* __restrict__ Wh, uint4* __restrict__ whp4) {
  int id = blockIdx.x * 256 + threadIdx.x;     // 32768
  int kb = id >> 10, g = id & 1023;
  const float* p = Wh + (size_t)g * HH + kb * 8;
  uint4 o;
  o.x = pkf16(p[0], p[1]); o.y = pkf16(p[2], p[3]);
  o.z = pkf16(p[4], p[5]); o.w = pkf16(p[6], p[7]);
  whp4[id] = o;
}

__global__ void prep_wi(const float* __restrict__ Wi, uint4* __restrict__ wip4) {
  int id = blockIdx.x * 256 + threadIdx.x;     // 16384
  int kp4 = id >> 10, g = id & 1023;
  const float* p = Wi + (size_t)g * DD + kp4 * 8;
  uint4 o;
  o.x = pkf16(p[0], p[1]); o.y = pkf16(p[2], p[3]);
  o.z = pkf16(p[4], p[5]); o.w = pkf16(p[6], p[7]);
  wip4[id] = o;
}

__global__ void flags_init(int* flags) { flags[threadIdx.x] = 0; }

// ---------------- xproj GEMM: xph[ml][g] = sum_d x[b][t][d]*Wi[g][d] + bi[g]+bh[g]
__global__ __launch_bounds__(256) void xproj_gemm(
    const float* __restrict__ x, const uint4* __restrict__ wip4,
    const float* __restrict__ bi, const float* __restrict__ bh,
    _Float16* __restrict__ xph, int m0) {
  __shared__ _Float16 xl[16][128];
  const int tid = threadIdx.x;
  const int mt = blockIdx.x, gt = blockIdx.y;
  const int g = gt * 256 + tid;
#pragma unroll
  for (int i = 0; i < 8; ++i) {
    int idx = i * 256 + tid;          // 0..2047
    int p = idx >> 7, d = idx & 127;
    int m = m0 + mt * 16 + p;         // global m = t*64+b
    xl[p][d] = (_Float16)x[(size_t)(m & 63) * (T_TOT * DD) + (size_t)(m >> 6) * DD + d];
  }
  __syncthreads();
  float acc[16];
#pragma unroll
  for (int p = 0; p < 16; ++p) acc[p] = 0.f;
#pragma unroll
  for (int kp4 = 0; kp4 < 16; ++kp4) {
    uint4 w = wip4[kp4 * GG + g];
#pragma unroll
    for (int p = 0; p < 16; ++p) {
      uint4 hv = *(const uint4*)(&xl[p][kp4 * 8]);   // uniform addr -> broadcast
      acc[p] = fdot2(w.x, hv.x, acc[p]);
      acc[p] = fdot2(w.y, hv.y, acc[p]);
      acc[p] = fdot2(w.z, hv.z, acc[p]);
      acc[p] = fdot2(w.w, hv.w, acc[p]);
    }
  }
  float bsum = bi[g] + bh[g];
#pragma unroll
  for (int p = 0; p < 16; ++p) {
    int ml = mt * 16 + p;
    xph[(size_t)ml * GG + g] = (_Float16)(acc[p] + bsum);
  }
}

// ---------------- scan v10: 4 blocks per batch (one gate type each), 256 blocks.
// Block bid: q = bid>>6 (gate type), b = bid&63 (batch) -> all 4 blocks of a
// batch share bid%8 (same XCD slot). 512 threads: wave w, kh = w>>2 (k-half,
// wave-uniform), 64 gates per wave. Weights: 16 uint4 = 64 VGPR per thread —
// fully register-resident under the 128-reg cap. Per-step cross-block exchange
// of 256 activations via agent-scope atomics + flag (release/acquire).
__global__ __launch_bounds__(512) void lstm_scan(
    const uint4* __restrict__ whp4, const _Float16* __restrict__ xphf,
    const float* __restrict__ lna_g, const float* __restrict__ lna_b,
    const float* __restrict__ ln_g, const float* __restrict__ ln_b,
    _Float16* __restrict__ hs16,
    _Float16* __restrict__ hxst, float* __restrict__ cxst,
    float* acts, int* flags, int t0, int ct) {
  __shared__ _Float16 hx16[HH];    // 512 B
  __shared__ float part[512];      // 2 KB  (k-half partial sums)
  __shared__ float gactL[HH];      // 1 KB  (this block's activations)
  __shared__ float red[8];
  __shared__ float red2[8];

  const int tid = threadIdx.x, bid = blockIdx.x;
  const int q = bid >> 6, b = bid & 63;
  const int lane = tid & 63, w = tid >> 6;
  const int khu = __builtin_amdgcn_readfirstlane(w >> 2);   // wave-uniform k-half
  const int gl = (w & 3) * 64 + lane;                       // local gate 0..255
  const int gG = q * 256 + gl;

  uint4 wr[16];
#pragma unroll
  for (int j = 0; j < 16; ++j) wr[j] = whp4[(khu * 16 + j) * 1024 + gG];

  float lgE = 0.f, lbE = 0.f, lng = 0.f, lnb = 0.f, cx = 0.f;
  if (tid < HH) {
    lgE = lna_g[q * 256 + tid]; lbE = lna_b[q * 256 + tid];
    lng = ln_g[tid]; lnb = ln_b[tid];
    if (t0 == 0) hx16[tid] = (_Float16)0.f;
    else { hx16[tid] = hxst[b * HH + tid]; cx = cxst[b * HH + tid]; }
  }
  __syncthreads();

  const _Float16* xr = xphf + b * GG + gG;
  int* flagB = flags + b * 4;
  _Float16* hsp = hs16 + (size_t)b * HH + tid;   // used by tid<256, q==0

  _Float16 x16 = xr[0];
  for (int tl = 0; tl < ct; ++tl) {
    const int sl = tl & 1;
    const int target = t0 + tl + 1;
    uint2 hp = *(const uint2*)(hx16 + 4 * lane);   // lane l holds hx dwords 2l,2l+1
    float a0 = (khu == 0) ? (float)x16 : 0.f, a1 = 0.f, a2 = 0.f, a3 = 0.f;
    if (tl + 1 < ct) x16 = xr[(size_t)(tl + 1) * (BB * GG)];
#pragma unroll
    for (int j = 0; j < 16; ++j) {
      int kb = khu * 16 + j;                       // wave-uniform -> readlane legal
      u32 h0 = (u32)__builtin_amdgcn_readlane((int)hp.x, 2 * kb);
      u32 h1 = (u32)__builtin_amdgcn_readlane((int)hp.y, 2 * kb);
      u32 h2 = (u32)__builtin_amdgcn_readlane((int)hp.x, 2 * kb + 1);
      u32 h3 = (u32)__builtin_amdgcn_readlane((int)hp.y, 2 * kb + 1);
      a0 = fdot2(wr[j].x, h0, a0);
      a1 = fdot2(wr[j].y, h1, a1);
      a2 = fdot2(wr[j].z, h2, a2);
      a3 = fdot2(wr[j].w, h3, a3);
    }
    part[khu * 256 + gl] = (a0 + a1) + (a2 + a3);
    __syncthreads();                                  // P: partials ready

    float av = 0.f, val = 0.f;
    if (tid < HH) {
      val = part[tid] + part[HH + tid];
      float s = val, ss = val * val;
#pragma unroll
      for (int m = 1; m <= 32; m <<= 1) {
        s += __shfl_xor(s, m, 64);
        ss += __shfl_xor(ss, m, 64);
      }
      int wid = tid >> 6;
      if (lane == 0) { red[wid] = s; red[4 + wid] = ss; }
    }
    __syncthreads();                                  // B1: red ready
    if (tid < HH) {
      float S = red[0] + red[1] + red[2] + red[3];
      float SS = red[4] + red[5] + red[6] + red[7];
      float mean = S * (1.f / HH);
      float var = SS * (1.f / HH) - mean * mean;
      float gn = (val - mean) * rsqrtf(var + LN_EPS) * lgE + lbE;
      av = (q == 2) ? fast_tanh(gn) : fast_sigmoid(gn);   // q block-uniform
      gactL[tid] = av;
      __hip_atomic_store(&acts[(((size_t)b * 4 + q) * 2 + sl) * HH + tid], av,
                         __ATOMIC_RELAXED, __HIP_MEMORY_SCOPE_AGENT);
      __threadfence();
    }
    __syncthreads();                                  // B2: stores drained
    if (tid == 0)
      __hip_atomic_store(&flagB[q], target, __ATOMIC_RELEASE, __HIP_MEMORY_SCOPE_AGENT);
    if (tid < 4 && tid != q) {
      int spins = 0;
      while (__hip_atomic_load(&flagB[tid], __ATOMIC_ACQUIRE, __HIP_MEMORY_SCOPE_AGENT) < target) {
        __builtin_amdgcn_s_sleep(2);
        if (++spins > (1 << 30)) break;               // safety: no infinite hang
      }
    }
    __syncthreads();                                  // B3: peers ready
    float cy = 0.f, go = 0.f;
    if (tid < HH) {
      size_t base = ((size_t)b * 4) * 2 * HH + (size_t)sl * HH + tid;
      float gi = (q == 0) ? gactL[tid]
               : __hip_atomic_load(&acts[base + 0 * 2 * HH], __ATOMIC_RELAXED, __HIP_MEMORY_SCOPE_AGENT);
      float gf = (q == 1) ? gactL[tid]
               : __hip_atomic_load(&acts[base + 1 * 2 * HH], __ATOMIC_RELAXED, __HIP_MEMORY_SCOPE_AGENT);
      float gc = (q == 2) ? gactL[tid]
               : __hip_atomic_load(&acts[base + 2 * 2 * HH], __ATOMIC_RELAXED, __HIP_MEMORY_SCOPE_AGENT);
      go       = (q == 3) ? gactL[tid]
               : __hip_atomic_load(&acts[base + 3 * 2 * HH], __ATOMIC_RELAXED, __HIP_MEMORY_SCOPE_AGENT);
      cy = gf * cx + gi * gc;
      cx = cy;
      float s2 = cy, ss2 = cy * cy;
#pragma unroll
      for (int m = 1; m <= 32; m <<= 1) {
        s2 += __shfl_xor(s2, m, 64);
        ss2 += __shfl_xor(ss2, m, 64);
      }
      int wid = tid >> 6;
      if (lane == 0) { red2[wid] = s2; red2[4 + wid] = ss2; }
    }
    __syncthreads();                                  // B4: red2 ready
    if (tid < HH) {
      float S2 = red2[0] + red2[1] + red2[2] + red2[3];
      float SS2 = red2[4] + red2[5] + red2[6] + red2[7];
      float mc = S2 * (1.f / HH);
      float vc = SS2 * (1.f / HH) - mc * mc;
      float cyn = (cy - mc) * rsqrtf(vc + LN_EPS) * lng + lnb;
      float hy = go * fast_tanh(cyn);
      hx16[tid] = (_Float16)hy;
      if (q == 0) hsp[(size_t)(t0 + tl) * (BB * HH)] = (_Float16)hy;
    }
    __syncthreads();                                  // B5: hx ready for next step
  }
  if (q == 0 && tid < HH) { hxst[b * HH + tid] = hx16[tid]; cxst[b * HH + tid] = cx; }
}

// ---------------- out GEMM: out[b][t][o] = relu(sum_h hs[t][b][h]*Wf[o][h] + bf[o])
__global__ __launch_bounds__(256) void out_gemm(
    const _Float16* __restrict__ hs16, const float* __restrict__ Wf,
    const float* __restrict__ bf, float* __restrict__ out) {
  __shared__ u32 wfl[128][64];    // pairs [kp][o], 32KB
  __shared__ u32 hsl[16][132];    // pairs [p][kp], padded
  const int tid = threadIdx.x;
  const int mbase = blockIdx.x * 16;
#pragma unroll
  for (int i = 0; i < 32; ++i) {  // 8192 pairs of Wf
    int idx = i * 256 + tid;
    int kp = idx >> 6, o = idx & 63;
    wfl[kp][o] = pkf16(Wf[o * HH + kp * 2], Wf[o * HH + kp * 2 + 1]);
  }
#pragma unroll
  for (int i = 0; i < 8; ++i) {   // 2048 pairs of hs
    int idx = i * 256 + tid;
    int p = idx >> 7, kp = idx & 127;
    hsl[p][kp] = *(const u32*)(hs16 + (size_t)(mbase + p) * HH + kp * 2);
  }
  __syncthreads();
  const int o = tid & 63, mi = tid >> 6;
  float bfo = bf[o];
#pragma unroll
  for (int mm = mi; mm < 16; mm += 4) {
    float a0 = bfo, a1 = 0.f, a2 = 0.f, a3 = 0.f;
#pragma unroll
    for (int kp = 0; kp < 128; kp += 4) {
      a0 = fdot2(wfl[kp + 0][o], hsl[mm][kp + 0], a0);
      a1 = fdot2(wfl[kp + 1][o], hsl[mm][kp + 1], a1);
      a2 = fdot2(wfl[kp + 2][o], hsl[mm][kp + 2], a2);
      a3 = fdot2(wfl[kp + 3][o], hsl[mm][kp + 3], a3);
    }
    float r = (a0 + a1) + (a2 + a3);
    int m = mbase + mm;
    out[(size_t)(m & 63) * (T_TOT * OO) + (size_t)(m >> 6) * OO + o] = fmaxf(r, 0.f);
  }
}

extern "C" void kernel_launch(void* const* d_in, const int* in_sizes, int n_in,
                              void* d_out, int out_size, void* d_ws, size_t ws_size,
                              hipStream_t stream) {
  if (n_in < 11) return;
  const float* x    = (const float*)d_in[0];
  const float* Wi   = (const float*)d_in[1];
  const float* bi   = (const float*)d_in[2];
  const float* Wh   = (const float*)d_in[3];
  const float* bh   = (const float*)d_in[4];
  const float* lnag = (const float*)d_in[5];
  const float* lnab = (const float*)d_in[6];
  const float* lng  = (const float*)d_in[7];
  const float* lnb  = (const float*)d_in[8];
  const float* Wf   = (const float*)d_in[9];
  const float* bf   = (const float*)d_in[10];
  float* out = (float*)d_out;

  char* ws = (char*)d_ws;
  uint4* whp4 = (uint4*)ws;                                  // 512 KB
  uint4* wip4 = (uint4*)(ws + (512 << 10));                  // 256 KB
  int* flags = (int*)(ws + (768 << 10));                     // 1 KB (256 ints)
  float* acts = (float*)(ws + (1 << 20));                    // 512 KB (64*4*2*256 f32)
  _Float16* hs16 = (_Float16*)(ws + (2 << 20));              // 32 MB
  _Float16* hxst = (_Float16*)(ws + (2 << 20) + (32 << 20)); // 32 KB
  float* cxst = (float*)(ws + (2 << 20) + (32 << 20) + (64 << 10)); // 64 KB
  const size_t xph_off = (size_t)36 << 20;
  _Float16* xph = (_Float16*)(ws + xph_off);

  size_t avail = ws_size > xph_off ? ws_size - xph_off : 0;
  int ct = T_TOT;
  while (ct > 1 && (size_t)ct * (BB * GG * 2) > avail) ct >>= 1;

  prep_wh<<<128, 256, 0, stream>>>(Wh, whp4);
  prep_wi<<<64, 256, 0, stream>>>(Wi, wip4);
  flags_init<<<1, 256, 0, stream>>>(flags);
  for (int t0 = 0; t0 < T_TOT; t0 += ct) {
    xproj_gemm<<<dim3((ct * BB) / 16, 4), 256, 0, stream>>>(x, wip4, bi, bh, xph, t0 * BB);
    lstm_scan<<<4 * BB, 512, 0, stream>>>(whp4, xph, lnag, lnab, lng, lnb,
                                          hs16, hxst, cxst, acts, flags, t0, ct);
  }
  out_gemm<<<(T_TOT * BB) / 16, 256, 0, stream>>>(hs16, Wf, bf, out);
}

// Round 10
// 3789.989 us; speedup vs baseline: 5.6172x; 5.6172x over previous
//
#include <hip/hip_runtime.h>

#define T_TOT 1024
#define BB 64
#define DD 128
#define HH 256
#define GG 1024
#define OO 64
#define LN_EPS 1e-3f
#define NV 23   // uint4 weight chunks per gate in VGPRs (92 dwords/thread)
#define NL 9    // uint4 weight chunks per gate in LDS (NV+NL=32); wl = 144KB static

typedef unsigned int u32;
typedef _Float16 h2 __attribute__((ext_vector_type(2)));

__device__ __forceinline__ float fdot2(u32 a, u32 b, float c) {
  return __builtin_amdgcn_fdot2(__builtin_bit_cast(h2, a), __builtin_bit_cast(h2, b), c, false);
}
__device__ __forceinline__ u32 pkf16(float lo, float hi) {
  h2 v = { (_Float16)lo, (_Float16)hi };
  return __builtin_bit_cast(u32, v);
}
__device__ __forceinline__ float fast_sigmoid(float x) { return 1.0f / (1.0f + __expf(-x)); }
__device__ __forceinline__ float fast_tanh(float x) { return 2.0f / (1.0f + __expf(-2.0f * x)) - 1.0f; }

// ---------------- prep: pack Wh (4H x H) into f16 pairs, chunked by 8 along H ----
__global__ void prep_wh(const float* __restrict__ Wh, uint4* __restrict__ whp4) {
  int id = blockIdx.x * 256 + threadIdx.x;     // 32768
  int kb = id >> 10, g = id & 1023;
  const float* p = Wh + (size_t)g * HH + kb * 8;
  uint4 o;
  o.x = pkf16(p[0], p[1]); o.y = pkf16(p[2], p[3]);
  o.z = pkf16(p[4], p[5]); o.w = pkf16(p[6], p[7]);
  whp4[id] = o;
}

__global__ void prep_wi(const float* __restrict__ Wi, uint4* __restrict__ wip4) {
  int id = blockIdx.x * 256 + threadIdx.x;     // 16384
  int kp4 = id >> 10, g = id & 1023;
  const float* p = Wi + (size_t)g * DD + kp4 * 8;
  uint4 o;
  o.x = pkf16(p[0], p[1]); o.y = pkf16(p[2], p[3]);
  o.z = pkf16(p[4], p[5]); o.w = pkf16(p[6], p[7]);
  wip4[id] = o;
}

// ---------------- xproj GEMM: xph[ml][g] = sum_d x[b][t][d]*Wi[g][d] + bi[g]+bh[g]
__global__ __launch_bounds__(256) void xproj_gemm(
    const float* __restrict__ x, const uint4* __restrict__ wip4,
    const float* __restrict__ bi, const float* __restrict__ bh,
    _Float16* __restrict__ xph, int m0) {
  __shared__ _Float16 xl[16][128];
  const int tid = threadIdx.x;
  const int mt = blockIdx.x, gt = blockIdx.y;
  const int g = gt * 256 + tid;
#pragma unroll
  for (int i = 0; i < 8; ++i) {
    int idx = i * 256 + tid;          // 0..2047
    int p = idx >> 7, d = idx & 127;
    int m = m0 + mt * 16 + p;         // global m = t*64+b
    xl[p][d] = (_Float16)x[(size_t)(m & 63) * (T_TOT * DD) + (size_t)(m >> 6) * DD + d];
  }
  __syncthreads();
  float acc[16];
#pragma unroll
  for (int p = 0; p < 16; ++p) acc[p] = 0.f;
#pragma unroll
  for (int kp4 = 0; kp4 < 16; ++kp4) {
    uint4 w = wip4[kp4 * GG + g];
#pragma unroll
    for (int p = 0; p < 16; ++p) {
      uint4 hv = *(const uint4*)(&xl[p][kp4 * 8]);   // uniform addr -> broadcast
      acc[p] = fdot2(w.x, hv.x, acc[p]);
      acc[p] = fdot2(w.y, hv.y, acc[p]);
      acc[p] = fdot2(w.z, hv.z, acc[p]);
      acc[p] = fdot2(w.w, hv.w, acc[p]);
    }
  }
  float bsum = bi[g] + bh[g];
#pragma unroll
  for (int p = 0; p < 16; ++p) {
    int ml = mt * 16 + p;
    xph[(size_t)ml * GG + g] = (_Float16)(acc[p] + bsum);
  }
}

// ---------------- scan v11: 1024 threads, ONE gate per thread.
// Per-thread register demand ~120 dwords (92 weight + ~28 state) honestly fits
// the 128-VGPR budget the allocator grants (static 152KB LDS -> 1 block/CU ->
// 16 waves = 4/SIMD). No spill, unlike 512-thr/2-gate (242-dword demand).
// hx distributed by v_readlane (VALU pipe), weights tail-streamed from LDS.
__global__ __launch_bounds__(1024) void lstm_scan(
    const uint4* __restrict__ whp4, const _Float16* __restrict__ xphf,
    const float* __restrict__ lna_g, const float* __restrict__ lna_b,
    const float* __restrict__ ln_g, const float* __restrict__ ln_b,
    _Float16* __restrict__ hs16,
    _Float16* __restrict__ hxst, float* __restrict__ cxst,
    int t0, int ct) {
  __shared__ uint4 wl[NL * 1024];          // 147456 B
  __shared__ _Float16 hx16[HH];            // 512 B
  __shared__ float red[32];
  __shared__ float red2[8];
  __shared__ float gact[GG];               // 4096 B  -> total ~152.2 KB

  const int tid = threadIdx.x;
  const int b = blockIdx.x;
  const int lane = tid & 63, wid = tid >> 6;
  const int q = tid >> 8;                  // gate type, wave-uniform

  uint4 wr[NV];
#pragma unroll
  for (int kb = 0; kb < NV; ++kb) wr[kb] = whp4[kb * 1024 + tid];
#pragma unroll
  for (int j = 0; j < NL; ++j) wl[j * 1024 + tid] = whp4[(NV + j) * 1024 + tid];

  float lg = lna_g[tid], lbv = lna_b[tid];
  float lng = 0.f, lnb = 0.f, cx = 0.f;
  if (tid < HH) {
    lng = ln_g[tid]; lnb = ln_b[tid];
    if (t0 == 0) hx16[tid] = (_Float16)0.f;
    else { hx16[tid] = hxst[b * HH + tid]; cx = cxst[b * HH + tid]; }
  }
  __syncthreads();

  const _Float16* xrow = xphf + b * GG + tid;
  _Float16* hsp = hs16 + (size_t)b * HH + (tid & 255);

  _Float16 x16 = xrow[0];
  for (int tl = 0; tl < ct; ++tl) {
    // lane l holds hx dwords 2l, 2l+1 (h[4l..4l+3]); 2-way bank alias = free
    uint2 hp = *(const uint2*)(hx16 + 4 * lane);
    float a0 = (float)x16, a1 = 0.f, a2 = 0.f, a3 = 0.f;
    if (tl + 1 < ct) x16 = xrow[(size_t)(tl + 1) * (BB * GG)];
#pragma unroll
    for (int kb = 0; kb < NV; ++kb) {
      u32 h0 = (u32)__builtin_amdgcn_readlane((int)hp.x, 2 * kb);
      u32 h1 = (u32)__builtin_amdgcn_readlane((int)hp.y, 2 * kb);
      u32 h2 = (u32)__builtin_amdgcn_readlane((int)hp.x, 2 * kb + 1);
      u32 h3 = (u32)__builtin_amdgcn_readlane((int)hp.y, 2 * kb + 1);
      a0 = fdot2(wr[kb].x, h0, a0);
      a1 = fdot2(wr[kb].y, h1, a1);
      a2 = fdot2(wr[kb].z, h2, a2);
      a3 = fdot2(wr[kb].w, h3, a3);
    }
#pragma unroll
    for (int j = 0; j < NL; ++j) {
      const int kb = NV + j;
      u32 h0 = (u32)__builtin_amdgcn_readlane((int)hp.x, 2 * kb);
      u32 h1 = (u32)__builtin_amdgcn_readlane((int)hp.y, 2 * kb);
      u32 h2 = (u32)__builtin_amdgcn_readlane((int)hp.x, 2 * kb + 1);
      u32 h3 = (u32)__builtin_amdgcn_readlane((int)hp.y, 2 * kb + 1);
      uint4 wA = wl[j * 1024 + tid];
      a0 = fdot2(wA.x, h0, a0);
      a1 = fdot2(wA.y, h1, a1);
      a2 = fdot2(wA.z, h2, a2);
      a3 = fdot2(wA.w, h3, a3);
    }
    float acc = (a0 + a1) + (a2 + a3);

    // gate-block LN over 256 gates of type q = waves {4q..4q+3}
    float s = acc, ss = acc * acc;
#pragma unroll
    for (int m = 1; m <= 32; m <<= 1) {
      s += __shfl_xor(s, m, 64);
      ss += __shfl_xor(ss, m, 64);
    }
    if (lane == 0) { red[wid] = s; red[16 + wid] = ss; }
    __syncthreads();                                  // B1
    float S  = red[4 * q] + red[4 * q + 1] + red[4 * q + 2] + red[4 * q + 3];
    float SS = red[16 + 4 * q] + red[16 + 4 * q + 1] + red[16 + 4 * q + 2] + red[16 + 4 * q + 3];
    float mean = S * (1.f / HH);
    float var = SS * (1.f / HH) - mean * mean;
    float gn = (acc - mean) * rsqrtf(var + LN_EPS) * lg + lbv;
    float av = (q == 2) ? fast_tanh(gn) : fast_sigmoid(gn);   // wave-uniform branch
    gact[tid] = av;
    __syncthreads();                                  // B2

    float cy = 0.f;
    if (tid < HH) {
      int h = tid;
      cy = gact[HH + h] * cx + gact[h] * gact[2 * HH + h];
      cx = cy;
      float s2 = cy, ss2 = cy * cy;
#pragma unroll
      for (int m = 1; m <= 32; m <<= 1) {
        s2 += __shfl_xor(s2, m, 64);
        ss2 += __shfl_xor(ss2, m, 64);
      }
      if (lane == 0) { red2[wid] = s2; red2[4 + wid] = ss2; }
    }
    __syncthreads();                                  // B3
    if (tid < HH) {
      int h = tid;
      float S2  = red2[0] + red2[1] + red2[2] + red2[3];
      float SS2 = red2[4] + red2[5] + red2[6] + red2[7];
      float mc = S2 * (1.f / HH);
      float vc = SS2 * (1.f / HH) - mc * mc;
      float cyn = (cy - mc) * rsqrtf(vc + LN_EPS) * lng + lnb;
      float hy = gact[3 * HH + h] * fast_tanh(cyn);
      hx16[h] = (_Float16)hy;
      hsp[(size_t)(t0 + tl) * (BB * HH)] = (_Float16)hy;
    }
    __syncthreads();                                  // B4
  }
  if (tid < HH) { hxst[b * HH + tid] = hx16[tid]; cxst[b * HH + tid] = cx; }
}

// ---------------- out GEMM: out[b][t][o] = relu(sum_h hs[t][b][h]*Wf[o][h] + bf[o])
__global__ __launch_bounds__(256) void out_gemm(
    const _Float16* __restrict__ hs16, const float* __restrict__ Wf,
    const float* __restrict__ bf, float* __restrict__ out) {
  __shared__ u32 wfl[128][64];    // pairs [kp][o], 32KB
  __shared__ u32 hsl[16][132];    // pairs [p][kp], padded
  const int tid = threadIdx.x;
  const int mbase = blockIdx.x * 16;
#pragma unroll
  for (int i = 0; i < 32; ++i) {  // 8192 pairs of Wf
    int idx = i * 256 + tid;
    int kp = idx >> 6, o = idx & 63;
    wfl[kp][o] = pkf16(Wf[o * HH + kp * 2], Wf[o * HH + kp * 2 + 1]);
  }
#pragma unroll
  for (int i = 0; i < 8; ++i) {   // 2048 pairs of hs
    int idx = i * 256 + tid;
    int p = idx >> 7, kp = idx & 127;
    hsl[p][kp] = *(const u32*)(hs16 + (size_t)(mbase + p) * HH + kp * 2);
  }
  __syncthreads();
  const int o = tid & 63, mi = tid >> 6;
  float bfo = bf[o];
#pragma unroll
  for (int mm = mi; mm < 16; mm += 4) {
    float a0 = bfo, a1 = 0.f, a2 = 0.f, a3 = 0.f;
#pragma unroll
    for (int kp = 0; kp < 128; kp += 4) {
      a0 = fdot2(wfl[kp + 0][o], hsl[mm][kp + 0], a0);
      a1 = fdot2(wfl[kp + 1][o], hsl[mm][kp + 1], a1);
      a2 = fdot2(wfl[kp + 2][o], hsl[mm][kp + 2], a2);
      a3 = fdot2(wfl[kp + 3][o], hsl[mm][kp + 3], a3);
    }
    float r = (a0 + a1) + (a2 + a3);
    int m = mbase + mm;
    out[(size_t)(m & 63) * (T_TOT * OO) + (size_t)(m >> 6) * OO + o] = fmaxf(r, 0.f);
  }
}

extern "C" void kernel_launch(void* const* d_in, const int* in_sizes, int n_in,
                              void* d_out, int out_size, void* d_ws, size_t ws_size,
                              hipStream_t stream) {
  if (n_in < 11) return;
  const float* x    = (const float*)d_in[0];
  const float* Wi   = (const float*)d_in[1];
  const float* bi   = (const float*)d_in[2];
  const float* Wh   = (const float*)d_in[3];
  const float* bh   = (const float*)d_in[4];
  const float* lnag = (const float*)d_in[5];
  const float* lnab = (const float*)d_in[6];
  const float* lng  = (const float*)d_in[7];
  const float* lnb  = (const float*)d_in[8];
  const float* Wf   = (const float*)d_in[9];
  const float* bf   = (const float*)d_in[10];
  float* out = (float*)d_out;

  char* ws = (char*)d_ws;
  uint4* whp4 = (uint4*)ws;                                  // 512 KB
  uint4* wip4 = (uint4*)(ws + (512 << 10));                  // 256 KB
  _Float16* hs16 = (_Float16*)(ws + (1 << 20));              // 32 MB
  _Float16* hxst = (_Float16*)(ws + (1 << 20) + (32 << 20)); // 32 KB
  float* cxst = (float*)(ws + (1 << 20) + (32 << 20) + (64 << 10)); // 64 KB
  const size_t xph_off = (size_t)35 << 20;
  _Float16* xph = (_Float16*)(ws + xph_off);

  size_t avail = ws_size > xph_off ? ws_size - xph_off : 0;
  int ct = T_TOT;
  while (ct > 1 && (size_t)ct * (BB * GG * 2) > avail) ct >>= 1;

  prep_wh<<<128, 256, 0, stream>>>(Wh, whp4);
  prep_wi<<<64, 256, 0, stream>>>(Wi, wip4);
  for (int t0 = 0; t0 < T_TOT; t0 += ct) {
    xproj_gemm<<<dim3((ct * BB) / 16, 4), 256, 0, stream>>>(x, wip4, bi, bh, xph, t0 * BB);
    lstm_scan<<<BB, 1024, 0, stream>>>(whp4, xph, lnag, lnab, lng, lnb,
                                       hs16, hxst, cxst, t0, ct);
  }
  out_gemm<<<(T_TOT * BB) / 16, 256, 0, stream>>>(hs16, Wf, bf, out);
}